// Round 1
// baseline (547.792 us; speedup 1.0000x reference)
//
#include <hip/hip_runtime.h>
#include <hip/hip_bf16.h>

typedef unsigned short u16;
typedef __attribute__((ext_vector_type(8))) short bf16x8;
typedef __attribute__((ext_vector_type(4))) float f32x4;
typedef __attribute__((ext_vector_type(8))) u16 u16x8;

__device__ __forceinline__ u16 f2bf(float x){
  __hip_bfloat16 h = __float2bfloat16(x);
  return __builtin_bit_cast(u16, h);
}
__device__ __forceinline__ float bf2f(u16 u){
  __hip_bfloat16 h = __builtin_bit_cast(__hip_bfloat16, u);
  return __bfloat162float(h);
}

// ---------------- LayerNorm over rows of 512 ----------------
__global__ __launch_bounds__(256) void ln_kernel(const float* __restrict__ in,
    const float* __restrict__ g, const float* __restrict__ b, float* __restrict__ out)
{
  int row = blockIdx.x, tid = threadIdx.x;
  const float* p = in + (size_t)row*512 + tid*2;
  float v0 = p[0], v1 = p[1];
  float s = v0+v1, ss = v0*v0+v1*v1;
  #pragma unroll
  for (int o=1;o<64;o<<=1){ s += __shfl_xor(s,o); ss += __shfl_xor(ss,o); }
  __shared__ float rs[4], rss[4];
  if ((tid&63)==0){ rs[tid>>6]=s; rss[tid>>6]=ss; }
  __syncthreads();
  s = rs[0]+rs[1]+rs[2]+rs[3]; ss = rss[0]+rss[1]+rss[2]+rss[3];
  float mean = s*(1.f/512.f);
  float var  = ss*(1.f/512.f) - mean*mean;
  float rstd = 1.f/sqrtf(var + 1e-5f);
  int d = tid*2;
  out[(size_t)row*512+d]   = (v0-mean)*rstd*g[d]   + b[d];
  out[(size_t)row*512+d+1] = (v1-mean)*rstd*g[d+1] + b[d+1];
}

// ---------------- conv input gather: xg[k=i*3+kk][h] = x1[i][2h-1+kk] ----------------
__global__ __launch_bounds__(256) void xg_kernel(const float* __restrict__ x1, float* __restrict__ xg)
{
  int kidx = blockIdx.x, h = threadIdx.x;
  int i = kidx/3, kk = kidx - i*3;
  int pos = 2*h - 1 + kk;
  float v = (pos >= 0 && pos < 512) ? x1[(size_t)i*512 + pos] : 0.f;
  xg[(size_t)kidx*256 + h] = v;
}

// ---------------- cached_k -> bf16 (skip masked t blocks) ----------------
__global__ __launch_bounds__(256) void cvt_cached(const float* __restrict__ ck,
    const int* __restrict__ mask, u16* __restrict__ kb)
{
  int flat = blockIdx.x*256 + threadIdx.x;   // 65536*32 total
  int row = flat >> 5, seg = flat & 31;
  if (mask[row>>9] == 0) return;
  const float* src = ck + (size_t)row*256 + seg*8;
  u16x8 o;
  #pragma unroll
  for (int j=0;j<8;j++) o[j] = f2bf(src[j]);
  *(u16x8*)(kb + (size_t)row*256 + seg*8) = o;
}

// ---------------- fp32 tiled GEMM, 64x64 tile, BK=16, 256 thr, opt bias/act/resid ----------------
// ACT: 0 none, 1 swish (x*sigmoid(1.702x))
template<int ACT>
__global__ __launch_bounds__(256) void gemm_f32(
    const float* __restrict__ A, const float* __restrict__ B,
    const float* __restrict__ bias, const float* __restrict__ resid,
    float* __restrict__ C, u16* __restrict__ Cbf, int M, int N, int K)
{
  __shared__ float As[16][68];
  __shared__ float Bs[16][68];
  int tid = threadIdx.x;
  int bm = blockIdx.y*64, bn = blockIdx.x*64;
  int tx = tid & 15, ty = tid >> 4;
  f32x4 acc[4];
  #pragma unroll
  for (int i=0;i<4;i++) acc[i]=(f32x4){0,0,0,0};
  int ar = tid >> 2, ac = (tid&3)*4;   // A: 64 rows x 16 k
  int br = tid >> 4, bc = (tid&15)*4;  // B: 16 k x 64 cols
  for (int k0=0;k0<K;k0+=16){
    __syncthreads();
    f32x4 av = *(const f32x4*)(A + (size_t)(bm+ar)*K + k0 + ac);
    f32x4 bv = *(const f32x4*)(B + (size_t)(k0+br)*N + bn + bc);
    As[ac+0][ar]=av[0]; As[ac+1][ar]=av[1]; As[ac+2][ar]=av[2]; As[ac+3][ar]=av[3];
    *(f32x4*)(&Bs[br][bc]) = bv;
    __syncthreads();
    #pragma unroll
    for (int k=0;k<16;k++){
      f32x4 a = *(const f32x4*)(&As[k][ty*4]);
      f32x4 b = *(const f32x4*)(&Bs[k][tx*4]);
      #pragma unroll
      for (int i=0;i<4;i++) acc[i] += a[i]*b;
    }
  }
  #pragma unroll
  for (int i=0;i<4;i++){
    int row = bm + ty*4 + i;
    #pragma unroll
    for (int j=0;j<4;j++){
      int col = bn + tx*4 + j;
      float v = acc[i][j];
      if (bias)  v += bias[col];
      if (ACT==1) v = v / (1.f + __expf(-1.702f*v));
      if (resid) v += resid[(size_t)row*N + col];
      if (C)   C[(size_t)row*N+col] = v;
      if (Cbf) Cbf[(size_t)row*N+col] = f2bf(v);
    }
  }
}

// ---------------- flash attention partial kernel (bf16 MFMA) ----------------
// block = 256 thr (4 waves), q-tile = 64 (16 q per wave), sub-chunk = 32 keys.
// S^T = K * Q^T (swapped) so both frags are contiguous bf16x8 loads.
// Writes per-chunk partials: m,l (f32) and O (bf16).
__global__ __launch_bounds__(256) void attn_flash(
    const u16* __restrict__ qb, const u16* __restrict__ keys,
    const int* __restrict__ mask, int keysPerChunk, int totalKeys, int maskLimit,
    u16* __restrict__ pO, float* __restrict__ pML)
{
  __shared__ u16 kr[32][264];      // padded rows: breaks d128-stride conflicts
  __shared__ u16 pl[4][16][40];    // per-wave P tile [q][key], padded
  int tid = threadIdx.x;
  int w = tid >> 6;
  int lane = tid & 63;
  int lq = lane & 15, lg = lane >> 4;
  int c = blockIdx.x, qt = blockIdx.y;
  int qbase = qt*64 + w*16;
  int kstart = c*keysPerChunk;
  int kend = kstart + keysPerChunk; if (kend > totalKeys) kend = totalKeys;

  bf16x8 qf[8];
  {
    const u16* qrow = qb + (size_t)(qbase+lq)*256 + lg*8;
    #pragma unroll
    for (int s=0;s<8;s++) qf[s] = *(const bf16x8*)(qrow + s*32);
  }
  f32x4 o[16];
  #pragma unroll
  for (int i=0;i<16;i++) o[i]=(f32x4){0,0,0,0};
  float m_run=-1e30f, l_run=0.f;
  bool any=false;

  for (int k0=kstart; k0<kend; k0+=32){
    if (mask && k0 < maskLimit && mask[k0>>9]==0) continue;   // masked: all-zero keys, handled in reduce
    any = true;
    __syncthreads();
    #pragma unroll
    for (int rep=0;rep<4;rep++){
      int flat = rep*256 + tid;
      int row = flat>>5, seg = flat&31;
      *(bf16x8*)(&kr[row][seg*8]) = *(const bf16x8*)(keys + (size_t)(k0+row)*256 + seg*8);
    }
    __syncthreads();
    // S^T tiles: keys (2x16) x q (16), accumulate over d=256
    f32x4 s0=(f32x4){0,0,0,0}, s1=(f32x4){0,0,0,0};
    #pragma unroll
    for (int s=0;s<8;s++){
      bf16x8 ka0 = *(const bf16x8*)(&kr[lq][s*32+lg*8]);
      bf16x8 ka1 = *(const bf16x8*)(&kr[16+lq][s*32+lg*8]);
      s0 = __builtin_amdgcn_mfma_f32_16x16x32_bf16(ka0, qf[s], s0, 0,0,0);
      s1 = __builtin_amdgcn_mfma_f32_16x16x32_bf16(ka1, qf[s], s1, 0,0,0);
    }
    // online softmax: lane holds, for q=lq, keys {lg*4+r} and {16+lg*4+r}
    float mx = -1e30f;
    #pragma unroll
    for (int r=0;r<4;r++){
      s0[r]*=0.0625f; s1[r]*=0.0625f;
      mx = fmaxf(mx, fmaxf(s0[r], s1[r]));
    }
    mx = fmaxf(mx, __shfl_xor(mx,16));
    mx = fmaxf(mx, __shfl_xor(mx,32));
    float m_new = fmaxf(m_run, mx);
    float corr = __expf(m_run - m_new);
    float ls = 0.f;
    float p0[4], p1[4];
    #pragma unroll
    for (int r=0;r<4;r++){
      p0[r] = __expf(s0[r]-m_new);
      p1[r] = __expf(s1[r]-m_new);
      ls += p0[r]+p1[r];
    }
    ls += __shfl_xor(ls,16); ls += __shfl_xor(ls,32);
    l_run = l_run*corr + ls; m_run = m_new;
    // P -> LDS (bf16), layout [q][key-in-32]
    #pragma unroll
    for (int r=0;r<4;r++){
      pl[w][lq][lg*4+r]    = f2bf(p0[r]);
      pl[w][lq][16+lg*4+r] = f2bf(p1[r]);
    }
    // rescale O (O-layout rows q'=lg*4+r; broadcast corr from lanes 0..15)
    float c0 = __shfl(corr, lg*4+0);
    float c1 = __shfl(corr, lg*4+1);
    float c2 = __shfl(corr, lg*4+2);
    float c3 = __shfl(corr, lg*4+3);
    #pragma unroll
    for (int dt=0;dt<16;dt++){
      o[dt][0]*=c0; o[dt][1]*=c1; o[dt][2]*=c2; o[dt][3]*=c3;
    }
    // PV: O[16q x 16d per dt] += P(16x32) * K(32x16)
    bf16x8 pa = *(const bf16x8*)(&pl[w][lq][lg*8]);
    #pragma unroll
    for (int dt=0;dt<16;dt++){
      bf16x8 kbv;
      #pragma unroll
      for (int j=0;j<8;j++) kbv[j] = (short)kr[lg*8+j][dt*16+lq];
      o[dt] = __builtin_amdgcn_mfma_f32_16x16x32_bf16(pa, kbv, o[dt], 0,0,0);
    }
  }
  if (!any) return;
  size_t base = (size_t)c*512 + qbase;
  if (lane < 16){
    pML[(base+lane)*2]   = m_run;
    pML[(base+lane)*2+1] = l_run;
  }
  #pragma unroll
  for (int dt=0;dt<16;dt++){
    #pragma unroll
    for (int r=0;r<4;r++){
      pO[(base + lg*4 + r)*256 + dt*16 + lq] = f2bf(o[dt][r]);
    }
  }
}

// ---------------- combine partials + masked-zero keys + self-attn + 1.5*q ----------------
__global__ __launch_bounds__(256) void attn_reduce(
    const u16* __restrict__ pO, const float* __restrict__ pML,
    const u16* __restrict__ pOs, const float* __restrict__ pMLs,
    const int* __restrict__ mask, const float* __restrict__ qf,
    float* __restrict__ attn_out)
{
  int q = blockIdx.x, d = threadIdx.x;
  int cnt0 = 0;
  for (int t=0;t<128;t++) cnt0 += (mask[t]==0) ? 1 : 0;
  float m_g = (cnt0>0) ? 0.f : -1e30f;     // masked keys have score exactly 0
  for (int c=0;c<65;c++){
    bool valid = (c==64) || (mask[2*c]!=0) || (mask[2*c+1]!=0);
    if (valid) m_g = fmaxf(m_g, pML[((size_t)c*512+q)*2]);
  }
  float denom = (cnt0>0) ? (512.f*(float)cnt0)*__expf(-m_g) : 0.f;
  float num = 0.f;
  for (int c=0;c<65;c++){
    bool valid = (c==64) || (mask[2*c]!=0) || (mask[2*c+1]!=0);
    if (!valid) continue;
    float m = pML[((size_t)c*512+q)*2];
    float l = pML[((size_t)c*512+q)*2+1];
    float wgt = __expf(m - m_g);
    denom += l*wgt;
    num += bf2f(pO[((size_t)c*512+q)*256 + d]) * wgt;
  }
  float big = num/denom;
  float lsx = pMLs[q*2+1];
  float sv = bf2f(pOs[(size_t)q*256+d]) / lsx;
  // atten = big + q + 0.5*(self + q) = big + 0.5*self + 1.5*q
  attn_out[(size_t)q*256+d] = big + 0.5f*sv + 1.5f*qf[(size_t)q*256+d];
}

extern "C" void kernel_launch(void* const* d_in, const int* in_sizes, int n_in,
                              void* d_out, int out_size, void* d_ws, size_t ws_size,
                              hipStream_t stream)
{
  const float* x    = (const float*)d_in[0];
  const float* ck   = (const float*)d_in[1];
  const float* ln1g = (const float*)d_in[2];
  const float* ln1b = (const float*)d_in[3];
  const float* ln2g = (const float*)d_in[4];
  const float* ln2b = (const float*)d_in[5];
  const float* wk   = (const float*)d_in[6];
  const float* wc   = (const float*)d_in[7];
  const float* apw  = (const float*)d_in[8];
  const float* apb  = (const float*)d_in[9];
  const float* fcw  = (const float*)d_in[10];
  const float* fcb  = (const float*)d_in[11];
  const float* pjw  = (const float*)d_in[12];
  const float* pjb  = (const float*)d_in[13];
  const int*   mask = (const int*)d_in[14];
  float* out = (float*)d_out;

  char* wsb = (char*)d_ws;
  float* x1   = (float*)(wsb + 0);          // 512x512 f32
  float* xg   = (float*)(wsb + 1048576);    // 1536x256 f32
  float* qf32 = (float*)(wsb + 2621440);    // 512x256 f32
  float* x2   = (float*)(wsb + 3145728);    // 512x512 f32
  float* x2n  = (float*)(wsb + 4194304);    // 512x512 f32
  float* h    = (float*)(wsb + 5242880);    // 512x2048 f32
  float* aout = (float*)(wsb + 9437184);    // 512x256 f32
  u16*   qbf  = (u16*)(wsb + 9961472);      // 512x256 bf16
  u16*   kbf  = (u16*)(wsb + 10223616);     // 66048x256 bf16
  float* pML  = (float*)(wsb + 44040192);   // 65x512x2 f32
  float* pMLs = (float*)(wsb + 44306432);   // 512x2 f32
  u16*   pO   = (u16*)(wsb + 44310528);     // 65x512x256 bf16
  u16*   pOs  = (u16*)(wsb + 61349888);     // 512x256 bf16

  ln_kernel<<<512,256,0,stream>>>(x, ln1g, ln1b, x1);
  xg_kernel<<<1536,256,0,stream>>>(x1, xg);
  // q = w_compress_k @ xg ; k_cur = w_compress_cur @ xg (bf16 into key buffer tail)
  gemm_f32<0><<<dim3(4,8),256,0,stream>>>(wk, xg, nullptr, nullptr, qf32, qbf, 512,256,1536);
  gemm_f32<0><<<dim3(4,8),256,0,stream>>>(wc, xg, nullptr, nullptr, nullptr, kbf + (size_t)65536*256, 512,256,1536);
  cvt_cached<<<8192,256,0,stream>>>(ck, mask, kbf);
  // big attention over 66048 keys, 65 chunks of 1024 (last = 512)
  attn_flash<<<dim3(65,8),256,0,stream>>>(qbf, kbf, mask, 1024, 66048, 65536, pO, pML);
  // self attention: keys = q itself, 1 chunk of 512
  attn_flash<<<dim3(1,8),256,0,stream>>>(qbf, qbf, nullptr, 512, 512, 0, pOs, pMLs);
  attn_reduce<<<512,256,0,stream>>>(pO, pML, pOs, pMLs, mask, qf32, aout);
  // x2 = x1 + atten@ap_w + ap_b
  gemm_f32<0><<<dim3(8,8),256,0,stream>>>(aout, apw, apb, x1, x2, nullptr, 512,512,256);
  ln_kernel<<<512,256,0,stream>>>(x2, ln2g, ln2b, x2n);
  // h = swish(x2n@fc_w + fc_b)
  gemm_f32<1><<<dim3(32,8),256,0,stream>>>(x2n, fcw, fcb, nullptr, h, nullptr, 512,2048,512);
  // out = x2 + h@proj_w + proj_b
  gemm_f32<0><<<dim3(8,8),256,0,stream>>>(h, pjw, pjb, x2, out, nullptr, 512,512,2048);
}

// Round 3
// 359.550 us; speedup vs baseline: 1.5235x; 1.5235x over previous
//
#include <hip/hip_runtime.h>
#include <hip/hip_bf16.h>

typedef unsigned short u16;
typedef __attribute__((ext_vector_type(8))) short bf16x8;
typedef __attribute__((ext_vector_type(4))) float f32x4;
typedef __attribute__((ext_vector_type(8))) u16 u16x8;

__device__ __forceinline__ u16 f2bf(float x){
  __hip_bfloat16 h = __float2bfloat16(x);
  return __builtin_bit_cast(u16, h);
}
__device__ __forceinline__ float bf2f(u16 u){
  __hip_bfloat16 h = __builtin_bit_cast(__hip_bfloat16, u);
  return __bfloat162float(h);
}

// ---------------- LayerNorm over rows of 512 ----------------
template<bool BF>
__global__ __launch_bounds__(256) void ln_kernel(const float* __restrict__ in,
    const float* __restrict__ g, const float* __restrict__ b,
    float* __restrict__ outf, u16* __restrict__ outb)
{
  int row = blockIdx.x, tid = threadIdx.x;
  const float* p = in + (size_t)row*512 + tid*2;
  float v0 = p[0], v1 = p[1];
  float s = v0+v1, ss = v0*v0+v1*v1;
  #pragma unroll
  for (int o=1;o<64;o<<=1){ s += __shfl_xor(s,o); ss += __shfl_xor(ss,o); }
  __shared__ float rs[4], rss[4];
  if ((tid&63)==0){ rs[tid>>6]=s; rss[tid>>6]=ss; }
  __syncthreads();
  s = rs[0]+rs[1]+rs[2]+rs[3]; ss = rss[0]+rss[1]+rss[2]+rss[3];
  float mean = s*(1.f/512.f);
  float var  = ss*(1.f/512.f) - mean*mean;
  float rstd = 1.f/sqrtf(var + 1e-5f);
  int d = tid*2;
  float o0 = (v0-mean)*rstd*g[d]   + b[d];
  float o1 = (v1-mean)*rstd*g[d+1] + b[d+1];
  if (BF){
    outb[(size_t)row*512+d]   = f2bf(o0);
    outb[(size_t)row*512+d+1] = f2bf(o1);
  } else {
    outf[(size_t)row*512+d]   = o0;
    outf[(size_t)row*512+d+1] = o1;
  }
}

// ---------------- conv input gather (transposed, bf16): xgT[h][k=i*3+kk] = x1[i][2h-1+kk] ----------------
__global__ __launch_bounds__(256) void xgT_kernel(const float* __restrict__ x1, u16* __restrict__ xgT)
{
  int h = blockIdx.x, tid = threadIdx.x;
  #pragma unroll
  for (int rep=0;rep<6;rep++){
    int k = rep*256 + tid;
    int i = k/3, kk = k - i*3;
    int pos = 2*h - 1 + kk;
    float v = (pos >= 0 && pos < 512) ? x1[(size_t)i*512 + pos] : 0.f;
    xgT[(size_t)h*1536 + k] = f2bf(v);
  }
}

// ---------------- plain f32 -> bf16 convert (8 elems/thread) ----------------
__global__ __launch_bounds__(256) void cvt_f2b(const float* __restrict__ in, u16* __restrict__ out)
{
  size_t i = (size_t)(blockIdx.x*256 + threadIdx.x)*8;
  const float* p = in + i;
  u16x8 o;
  #pragma unroll
  for (int j=0;j<8;j++) o[j] = f2bf(p[j]);
  *(u16x8*)(out + i) = o;
}

// ---------------- transpose + convert: in f32 [K][N] -> out bf16 [N][K] ----------------
__global__ __launch_bounds__(256) void transcvt(const float* __restrict__ in, u16* __restrict__ out, int K, int N)
{
  __shared__ float t[32][33];
  int nb = blockIdx.x*32, kb = blockIdx.y*32;
  int tx = threadIdx.x & 31, ty = threadIdx.x >> 5;
  #pragma unroll
  for (int i=0;i<32;i+=8) t[ty+i][tx] = in[(size_t)(kb+ty+i)*N + nb+tx];
  __syncthreads();
  #pragma unroll
  for (int i=0;i<32;i+=8) out[(size_t)(nb+ty+i)*K + kb+tx] = f2bf(t[tx][ty+i]);
}

// ---------------- cached_k -> bf16 (skip masked t blocks) ----------------
__global__ __launch_bounds__(256) void cvt_cached(const float* __restrict__ ck,
    const int* __restrict__ mask, u16* __restrict__ kb)
{
  int flat = blockIdx.x*256 + threadIdx.x;   // 65536*32 total
  int row = flat >> 5, seg = flat & 31;
  if (mask[row>>9] == 0) return;
  const float* src = ck + (size_t)row*256 + seg*8;
  u16x8 o;
  #pragma unroll
  for (int j=0;j<8;j++) o[j] = f2bf(src[j]);
  *(u16x8*)(kb + (size_t)row*256 + seg*8) = o;
}

// ---------------- bf16 MFMA GEMM: 1 wave/block, 32x32 tile, direct-global frags ----------------
// A: bf16 [M][K] row-major; B: bf16 [N][K] row-major (pre-transposed).
// ACT: 0 none, 1 swish. WF32: write f32 outF. WBF: write bf16 outB (split at rowSplit -> outB2).
template<int ACT, bool WF32, bool WBF>
__global__ __launch_bounds__(64) void gemm_bf(
    const u16* __restrict__ A, const u16* __restrict__ B,
    const float* __restrict__ bias, const float* __restrict__ resid,
    float* __restrict__ outF, u16* __restrict__ outB, u16* __restrict__ outB2,
    int rowSplit, int M, int N, int K)
{
  int lane = threadIdx.x;
  int lq = lane & 15, lg = lane >> 4;
  int m0 = blockIdx.y*32, n0 = blockIdx.x*32;
  f32x4 acc00={0,0,0,0}, acc01={0,0,0,0}, acc10={0,0,0,0}, acc11={0,0,0,0};
  const u16* pa0 = A + (size_t)(m0+lq)*K + lg*8;
  const u16* pa1 = pa0 + (size_t)16*K;
  const u16* pb0 = B + (size_t)(n0+lq)*K + lg*8;
  const u16* pb1 = pb0 + (size_t)16*K;
  #pragma unroll 2
  for (int k0=0;k0<K;k0+=32){
    bf16x8 a0 = *(const bf16x8*)(pa0+k0);
    bf16x8 a1 = *(const bf16x8*)(pa1+k0);
    bf16x8 b0 = *(const bf16x8*)(pb0+k0);
    bf16x8 b1 = *(const bf16x8*)(pb1+k0);
    acc00 = __builtin_amdgcn_mfma_f32_16x16x32_bf16(a0,b0,acc00,0,0,0);
    acc01 = __builtin_amdgcn_mfma_f32_16x16x32_bf16(a0,b1,acc01,0,0,0);
    acc10 = __builtin_amdgcn_mfma_f32_16x16x32_bf16(a1,b0,acc10,0,0,0);
    acc11 = __builtin_amdgcn_mfma_f32_16x16x32_bf16(a1,b1,acc11,0,0,0);
  }
  f32x4 accs[2][2] = {{acc00,acc01},{acc10,acc11}};
  #pragma unroll
  for (int mi=0;mi<2;mi++){
    #pragma unroll
    for (int r=0;r<4;r++){
      int row = m0 + mi*16 + lg*4 + r;
      #pragma unroll
      for (int ni=0;ni<2;ni++){
        int col = n0 + ni*16 + lq;
        float v = accs[mi][ni][r];
        if (bias)  v += bias[col];
        if (ACT==1) v = v/(1.f+__expf(-1.702f*v));
        if (resid) v += resid[(size_t)row*N+col];
        if (WF32) outF[(size_t)row*N+col] = v;
        if (WBF){
          if (row < rowSplit) outB[(size_t)row*N+col] = f2bf(v);
          else                outB2[(size_t)(row-rowSplit)*N+col] = f2bf(v);
        }
      }
    }
  }
}

// ---------------- flash attention partial kernel (bf16 MFMA) ----------------
__global__ __launch_bounds__(256) void attn_flash(
    const u16* __restrict__ qb, const u16* __restrict__ keys,
    const int* __restrict__ mask, int keysPerChunk, int totalKeys, int maskLimit,
    u16* __restrict__ pO, float* __restrict__ pML)
{
  __shared__ u16 kr[32][264];      // padded rows
  __shared__ u16 pl[4][16][40];    // per-wave P tile [q][key], padded
  int tid = threadIdx.x;
  int w = tid >> 6;
  int lane = tid & 63;
  int lq = lane & 15, lg = lane >> 4;
  int c = blockIdx.x, qt = blockIdx.y;
  int qbase = qt*64 + w*16;
  int kstart = c*keysPerChunk;
  int kend = kstart + keysPerChunk; if (kend > totalKeys) kend = totalKeys;

  bf16x8 qf[8];
  {
    const u16* qrow = qb + (size_t)(qbase+lq)*256 + lg*8;
    #pragma unroll
    for (int s=0;s<8;s++) qf[s] = *(const bf16x8*)(qrow + s*32);
  }
  f32x4 o[16];
  #pragma unroll
  for (int i=0;i<16;i++) o[i]=(f32x4){0,0,0,0};
  float m_run=-1e30f, l_run=0.f;
  bool any=false;

  for (int k0=kstart; k0<kend; k0+=32){
    if (mask && k0 < maskLimit && mask[k0>>9]==0) continue;
    any = true;
    __syncthreads();
    #pragma unroll
    for (int rep=0;rep<4;rep++){
      int flat = rep*256 + tid;
      int row = flat>>5, seg = flat&31;
      *(bf16x8*)(&kr[row][seg*8]) = *(const bf16x8*)(keys + (size_t)(k0+row)*256 + seg*8);
    }
    __syncthreads();
    f32x4 s0=(f32x4){0,0,0,0}, s1=(f32x4){0,0,0,0};
    #pragma unroll
    for (int s=0;s<8;s++){
      bf16x8 ka0 = *(const bf16x8*)(&kr[lq][s*32+lg*8]);
      bf16x8 ka1 = *(const bf16x8*)(&kr[16+lq][s*32+lg*8]);
      s0 = __builtin_amdgcn_mfma_f32_16x16x32_bf16(ka0, qf[s], s0, 0,0,0);
      s1 = __builtin_amdgcn_mfma_f32_16x16x32_bf16(ka1, qf[s], s1, 0,0,0);
    }
    float mx = -1e30f;
    #pragma unroll
    for (int r=0;r<4;r++){
      s0[r]*=0.0625f; s1[r]*=0.0625f;
      mx = fmaxf(mx, fmaxf(s0[r], s1[r]));
    }
    mx = fmaxf(mx, __shfl_xor(mx,16));
    mx = fmaxf(mx, __shfl_xor(mx,32));
    float m_new = fmaxf(m_run, mx);
    float corr = __expf(m_run - m_new);
    float ls = 0.f;
    float p0[4], p1[4];
    #pragma unroll
    for (int r=0;r<4;r++){
      p0[r] = __expf(s0[r]-m_new);
      p1[r] = __expf(s1[r]-m_new);
      ls += p0[r]+p1[r];
    }
    ls += __shfl_xor(ls,16); ls += __shfl_xor(ls,32);
    l_run = l_run*corr + ls; m_run = m_new;
    #pragma unroll
    for (int r=0;r<4;r++){
      pl[w][lq][lg*4+r]    = f2bf(p0[r]);
      pl[w][lq][16+lg*4+r] = f2bf(p1[r]);
    }
    float c0 = __shfl(corr, lg*4+0);
    float c1 = __shfl(corr, lg*4+1);
    float c2 = __shfl(corr, lg*4+2);
    float c3 = __shfl(corr, lg*4+3);
    #pragma unroll
    for (int dt=0;dt<16;dt++){
      o[dt][0]*=c0; o[dt][1]*=c1; o[dt][2]*=c2; o[dt][3]*=c3;
    }
    bf16x8 pa = *(const bf16x8*)(&pl[w][lq][lg*8]);
    #pragma unroll
    for (int dt=0;dt<16;dt++){
      bf16x8 kbv;
      #pragma unroll
      for (int j=0;j<8;j++) kbv[j] = (short)kr[lg*8+j][dt*16+lq];
      o[dt] = __builtin_amdgcn_mfma_f32_16x16x32_bf16(pa, kbv, o[dt], 0,0,0);
    }
  }
  if (!any) return;
  size_t base = (size_t)c*512 + qbase;
  if (lane < 16){
    pML[(base+lane)*2]   = m_run;
    pML[(base+lane)*2+1] = l_run;
  }
  #pragma unroll
  for (int dt=0;dt<16;dt++){
    #pragma unroll
    for (int r=0;r<4;r++){
      pO[(base + lg*4 + r)*256 + dt*16 + lq] = f2bf(o[dt][r]);
    }
  }
}

// ---------------- combine partials + masked-zero keys + self-attn + 1.5*q ----------------
__global__ __launch_bounds__(256) void attn_reduce(
    const u16* __restrict__ pO, const float* __restrict__ pML,
    const u16* __restrict__ pOs, const float* __restrict__ pMLs,
    const int* __restrict__ mask, const u16* __restrict__ qb,
    u16* __restrict__ attn_out)
{
  int q = blockIdx.x, d = threadIdx.x;
  int cnt0 = 0;
  for (int t=0;t<128;t++) cnt0 += (mask[t]==0) ? 1 : 0;
  float m_g = (cnt0>0) ? 0.f : -1e30f;
  for (int c=0;c<33;c++){
    bool valid = (c==32) || mask[4*c] || mask[4*c+1] || mask[4*c+2] || mask[4*c+3];
    if (valid) m_g = fmaxf(m_g, pML[((size_t)c*512+q)*2]);
  }
  float denom = (cnt0>0) ? (512.f*(float)cnt0)*__expf(-m_g) : 0.f;
  float num = 0.f;
  for (int c=0;c<33;c++){
    bool valid = (c==32) || mask[4*c] || mask[4*c+1] || mask[4*c+2] || mask[4*c+3];
    if (!valid) continue;
    float m = pML[((size_t)c*512+q)*2];
    float l = pML[((size_t)c*512+q)*2+1];
    float wgt = __expf(m - m_g);
    denom += l*wgt;
    num += bf2f(pO[((size_t)c*512+q)*256 + d]) * wgt;
  }
  float big = num/denom;
  float lsx = pMLs[q*2+1];
  float sv = bf2f(pOs[(size_t)q*256+d]) / lsx;
  attn_out[(size_t)q*256+d] = f2bf(big + 0.5f*sv + 1.5f*bf2f(qb[(size_t)q*256+d]));
}

extern "C" void kernel_launch(void* const* d_in, const int* in_sizes, int n_in,
                              void* d_out, int out_size, void* d_ws, size_t ws_size,
                              hipStream_t stream)
{
  const float* x    = (const float*)d_in[0];
  const float* ck   = (const float*)d_in[1];
  const float* ln1g = (const float*)d_in[2];
  const float* ln1b = (const float*)d_in[3];
  const float* ln2g = (const float*)d_in[4];
  const float* ln2b = (const float*)d_in[5];
  const float* wk   = (const float*)d_in[6];
  const float* wc   = (const float*)d_in[7];
  const float* apw  = (const float*)d_in[8];
  const float* apb  = (const float*)d_in[9];
  const float* fcw  = (const float*)d_in[10];
  const float* fcb  = (const float*)d_in[11];
  const float* pjw  = (const float*)d_in[12];
  const float* pjb  = (const float*)d_in[13];
  const int*   mask = (const int*)d_in[14];
  float* out = (float*)d_out;

  char* wsb = (char*)d_ws;
  float* x1    = (float*)(wsb + 0);          // 512x512 f32
  float* x2    = (float*)(wsb + 1048576);    // 512x512 f32
  u16*   aoutb = (u16*)  (wsb + 2097152);    // 512x256 bf16
  u16*   x2nb  = (u16*)  (wsb + 2359296);    // 512x512 bf16
  u16*   hb    = (u16*)  (wsb + 2883584);    // 512x2048 bf16
  u16*   xgT   = (u16*)  (wsb + 4980736);    // 256x1536 bf16
  u16*   wkcb  = (u16*)  (wsb + 5767168);    // 1024x1536 bf16 (wk stacked on wc)
  u16*   apT   = (u16*)  (wsb + 8912896);    // 512x256 bf16
  u16*   fcT   = (u16*)  (wsb + 9175040);    // 2048x512 bf16
  u16*   pjT   = (u16*)  (wsb + 11272192);   // 512x2048 bf16
  u16*   qbf   = (u16*)  (wsb + 13369344);   // 512x256 bf16
  u16*   kbf   = (u16*)  (wsb + 13631488);   // 66048x256 bf16
  float* pML   = (float*)(wsb + 47448064);   // 33x512x2 f32
  float* pMLs  = (float*)(wsb + 47583232);   // 512x2 f32
  u16*   pO    = (u16*)  (wsb + 47587328);   // 33x512x256 bf16
  u16*   pOs   = (u16*)  (wsb + 56238080);   // 512x256 bf16

  ln_kernel<false><<<512,256,0,stream>>>(x, ln1g, ln1b, x1, nullptr);
  xgT_kernel<<<256,256,0,stream>>>(x1, xgT);
  cvt_f2b<<<384,256,0,stream>>>(wk, wkcb);
  cvt_f2b<<<384,256,0,stream>>>(wc, wkcb + (size_t)512*1536);
  transcvt<<<dim3(16,8),256,0,stream>>>(apw, apT, 256, 512);
  transcvt<<<dim3(64,16),256,0,stream>>>(fcw, fcT, 512, 2048);
  transcvt<<<dim3(16,64),256,0,stream>>>(pjw, pjT, 2048, 512);
  cvt_cached<<<8192,256,0,stream>>>(ck, mask, kbf);

  // conv GEMM: [wk;wc](1024x1536) @ xgT^T -> q (rows<512) + k_cur (rows>=512)
  gemm_bf<0,false,true><<<dim3(8,32),64,0,stream>>>(wkcb, xgT, nullptr, nullptr,
      nullptr, qbf, kbf + (size_t)65536*256, 512, 1024, 256, 1536);

  // big attention over 66048 keys: 33 chunks of 2048 (last = 512)
  attn_flash<<<dim3(33,8),256,0,stream>>>(qbf, kbf, mask, 2048, 66048, 65536, pO, pML);
  // self attention
  attn_flash<<<dim3(1,8),256,0,stream>>>(qbf, qbf, nullptr, 512, 512, 0, pOs, pMLs);
  attn_reduce<<<512,256,0,stream>>>(pO, pML, pOs, pMLs, mask, qbf, aoutb);

  // x2 = x1 + atten@ap_w + ap_b
  gemm_bf<0,true,false><<<dim3(16,16),64,0,stream>>>(aoutb, apT, apb, x1,
      x2, nullptr, nullptr, 512, 512, 512, 256);
  ln_kernel<true><<<512,256,0,stream>>>(x2, ln2g, ln2b, nullptr, x2nb);
  // h = swish(x2n@fc_w + fc_b)
  gemm_bf<1,false,true><<<dim3(64,16),64,0,stream>>>(x2nb, fcT, fcb, nullptr,
      nullptr, hb, hb, 4096, 512, 2048, 512);
  // out = x2 + h@proj_w + proj_b
  gemm_bf<0,true,false><<<dim3(16,16),64,0,stream>>>(hb, pjT, pjb, x2,
      out, nullptr, nullptr, 512, 512, 512, 2048);
}

// Round 6
// 217.781 us; speedup vs baseline: 2.5153x; 1.6510x over previous
//
#include <hip/hip_runtime.h>
#include <hip/hip_bf16.h>

typedef unsigned short u16;
typedef unsigned int u32;
typedef __attribute__((ext_vector_type(8))) short bf16x8;
typedef __attribute__((ext_vector_type(4))) float f32x4;
typedef __attribute__((ext_vector_type(8))) u16 u16x8;

__device__ __forceinline__ u16 f2bf(float x){
  __hip_bfloat16 h = __float2bfloat16(x);
  return __builtin_bit_cast(u16, h);
}
__device__ __forceinline__ float bf2f(u16 u){
  __hip_bfloat16 h = __builtin_bit_cast(__hip_bfloat16, u);
  return __bfloat162float(h);
}

// ---------------- LayerNorm over rows of 512 ----------------
template<bool BF>
__global__ __launch_bounds__(256) void ln_kernel(const float* __restrict__ in,
    const float* __restrict__ g, const float* __restrict__ b,
    float* __restrict__ outf, u16* __restrict__ outb)
{
  int row = blockIdx.x, tid = threadIdx.x;
  const float* p = in + (size_t)row*512 + tid*2;
  float v0 = p[0], v1 = p[1];
  float s = v0+v1, ss = v0*v0+v1*v1;
  #pragma unroll
  for (int o=1;o<64;o<<=1){ s += __shfl_xor(s,o); ss += __shfl_xor(ss,o); }
  __shared__ float rs[4], rss[4];
  if ((tid&63)==0){ rs[tid>>6]=s; rss[tid>>6]=ss; }
  __syncthreads();
  s = rs[0]+rs[1]+rs[2]+rs[3]; ss = rss[0]+rss[1]+rss[2]+rss[3];
  float mean = s*(1.f/512.f);
  float var  = ss*(1.f/512.f) - mean*mean;
  float rstd = 1.f/sqrtf(var + 1e-5f);
  int d = tid*2;
  float o0 = (v0-mean)*rstd*g[d]   + b[d];
  float o1 = (v1-mean)*rstd*g[d+1] + b[d+1];
  if (BF){
    outb[(size_t)row*512+d]   = f2bf(o0);
    outb[(size_t)row*512+d+1] = f2bf(o1);
  } else {
    outf[(size_t)row*512+d]   = o0;
    outf[(size_t)row*512+d+1] = o1;
  }
}

// ---------------- conv input gather (transposed, bf16) ----------------
__global__ __launch_bounds__(256) void xgT_kernel(const float* __restrict__ x1, u16* __restrict__ xgT)
{
  int h = blockIdx.x, tid = threadIdx.x;
  #pragma unroll
  for (int rep=0;rep<6;rep++){
    int k = rep*256 + tid;
    int i = k/3, kk = k - i*3;
    int pos = 2*h - 1 + kk;
    float v = (pos >= 0 && pos < 512) ? x1[(size_t)i*512 + pos] : 0.f;
    xgT[(size_t)h*1536 + k] = f2bf(v);
  }
}

// ---------------- plain f32 -> bf16 convert (8 elems/thread) ----------------
__global__ __launch_bounds__(256) void cvt_f2b(const float* __restrict__ in, u16* __restrict__ out)
{
  size_t i = (size_t)(blockIdx.x*256 + threadIdx.x)*8;
  const float* p = in + i;
  u16x8 o;
  #pragma unroll
  for (int j=0;j<8;j++) o[j] = f2bf(p[j]);
  *(u16x8*)(out + i) = o;
}

// ---------------- transpose + convert: in f32 [K][N] -> out bf16 [N][K] ----------------
__global__ __launch_bounds__(256) void transcvt(const float* __restrict__ in, u16* __restrict__ out, int K, int N)
{
  __shared__ float t[32][33];
  int nb = blockIdx.x*32, kb = blockIdx.y*32;
  int tx = threadIdx.x & 31, ty = threadIdx.x >> 5;
  #pragma unroll
  for (int i=0;i<32;i+=8) t[ty+i][tx] = in[(size_t)(kb+ty+i)*N + nb+tx];
  __syncthreads();
  #pragma unroll
  for (int i=0;i<32;i+=8) out[(size_t)(nb+ty+i)*K + kb+tx] = f2bf(t[tx][ty+i]);
}

// ---------------- cached_k -> bf16 (skip masked t blocks) ----------------
__global__ __launch_bounds__(256) void cvt_cached(const float* __restrict__ ck,
    const int* __restrict__ mask, u16* __restrict__ kb)
{
  int flat = blockIdx.x*256 + threadIdx.x;   // 65536*32 total
  int row = flat >> 5, seg = flat & 31;
  if (mask[row>>9] == 0) return;
  const float* src = ck + (size_t)row*256 + seg*8;
  u16x8 o;
  #pragma unroll
  for (int j=0;j<8;j++) o[j] = f2bf(src[j]);
  *(u16x8*)(kb + (size_t)row*256 + seg*8) = o;
}

// ---------------- bf16 MFMA GEMM: 1 wave/block, 32x32 tile (round-3 verified) ----------------
template<int ACT, bool WF32, bool WBF>
__global__ __launch_bounds__(64) void gemm_bf(
    const u16* __restrict__ A, const u16* __restrict__ B,
    const float* __restrict__ bias, const float* __restrict__ resid,
    float* __restrict__ outF, u16* __restrict__ outB, u16* __restrict__ outB2,
    int rowSplit, int M, int N, int K)
{
  int lane = threadIdx.x;
  int lq = lane & 15, lg = lane >> 4;
  int m0 = blockIdx.y*32, n0 = blockIdx.x*32;
  f32x4 acc00={0,0,0,0}, acc01={0,0,0,0}, acc10={0,0,0,0}, acc11={0,0,0,0};
  const u16* pa0 = A + (size_t)(m0+lq)*K + lg*8;
  const u16* pa1 = pa0 + (size_t)16*K;
  const u16* pb0 = B + (size_t)(n0+lq)*K + lg*8;
  const u16* pb1 = pb0 + (size_t)16*K;
  #pragma unroll 2
  for (int k0=0;k0<K;k0+=32){
    bf16x8 a0 = *(const bf16x8*)(pa0+k0);
    bf16x8 a1 = *(const bf16x8*)(pa1+k0);
    bf16x8 b0 = *(const bf16x8*)(pb0+k0);
    bf16x8 b1 = *(const bf16x8*)(pb1+k0);
    acc00 = __builtin_amdgcn_mfma_f32_16x16x32_bf16(a0,b0,acc00,0,0,0);
    acc01 = __builtin_amdgcn_mfma_f32_16x16x32_bf16(a0,b1,acc01,0,0,0);
    acc10 = __builtin_amdgcn_mfma_f32_16x16x32_bf16(a1,b0,acc10,0,0,0);
    acc11 = __builtin_amdgcn_mfma_f32_16x16x32_bf16(a1,b1,acc11,0,0,0);
  }
  f32x4 accs[2][2] = {{acc00,acc01},{acc10,acc11}};
  #pragma unroll
  for (int mi=0;mi<2;mi++){
    #pragma unroll
    for (int r=0;r<4;r++){
      int row = m0 + mi*16 + lg*4 + r;
      #pragma unroll
      for (int ni=0;ni<2;ni++){
        int col = n0 + ni*16 + lq;
        float v = accs[mi][ni][r];
        if (bias)  v += bias[col];
        if (ACT==1) v = v/(1.f+__expf(-1.702f*v));
        if (resid) v += resid[(size_t)row*N+col];
        if (WF32) outF[(size_t)row*N+col] = v;
        if (WBF){
          if (row < rowSplit) outB[(size_t)row*N+col] = f2bf(v);
          else                outB2[(size_t)(row-rowSplit)*N+col] = f2bf(v);
        }
      }
    }
  }
}

// ---------------- flash attention partial kernel (v2: no tr_read, no shuffle-P) ----------------
// grid (66, 8): c<64 cached chunks (1024 keys), c=64 conv keys (512), c=65 self (keys=q).
// LDS layout per 32-key tile: elem(d,k) = (d>>4)*512 + k*16 + (d&15)  (16 KB, linear),
// staged via global_load_lds(16B) with pre-swizzled global addresses, double-buffered.
// No online max: scores q.k/16 are bounded (|s| <= ~20), exp is fp32/bf16-safe.
__global__ __launch_bounds__(256) void attn_flash(
    const u16* __restrict__ qb, const u16* __restrict__ keys,
    const int* __restrict__ mask,
    u16* __restrict__ pO, float* __restrict__ pL)
{
  __shared__ u16 kv[2][8192];
  __shared__ u16 pl[4][16][40];   // per-wave P tile [q][key], padded (round-3 verified)
  int tid = threadIdx.x;
  int w = tid >> 6, lane = tid & 63, lq = lane & 15, lg = lane >> 4;
  int c = blockIdx.x, qt = blockIdx.y;
  const u16* kp = keys;
  int kstart = c * 1024, off = 0, nt = 16;
  if (c == 65) { kp = qb; kstart = 0; }
  else if (c < 64) {
    int m0 = mask[2*c], m1 = mask[2*c+1];
    if (!m0 && !m1) return;
    off = m0 ? 0 : 512;
    nt = ((m0?1:0) + (m1?1:0)) * 16;
  }
  int qbase = qt*64 + w*16;

  bf16x8 qf[8];
  {
    const u16* qrow = qb + (size_t)(qbase+lq)*256 + lg*8;
    #pragma unroll
    for (int s=0;s<8;s++) qf[s] = *(const bf16x8*)(qrow + s*32);
  }
  f32x4 o[16];
  #pragma unroll
  for (int i=0;i<16;i++) o[i] = (f32x4){0,0,0,0};
  float l_acc = 0.f;

  auto kv3 = (__attribute__((address_space(3))) char*)&kv[0][0];
  const char* gbase = (const char*)kp + (size_t)(kstart+off)*512;

  #define STAGE(i, b) { \
    const char* tb = gbase + (size_t)(i)*16384; \
    _Pragma("unroll") \
    for (int rep=0; rep<4; rep++){ \
      int slot = rep*256 + tid; \
      int goff = ((slot&63)>>1)*512 + ((slot>>6)*16 + (slot&1)*8)*2; \
      __builtin_amdgcn_global_load_lds( \
        (const __attribute__((address_space(1))) unsigned*)(tb + goff), \
        (__attribute__((address_space(3))) unsigned*)(kv3 + (b)*16384 + (rep*256 + (tid & ~63))*16), \
        16, 0, 0); \
    } }

  STAGE(0, 0);
  for (int i=0; i<nt; i++){
    int cur = i & 1;
    if (i+1 < nt){
      STAGE(i+1, cur^1);
      asm volatile("s_waitcnt vmcnt(4)" ::: "memory");
    } else {
      asm volatile("s_waitcnt vmcnt(0)" ::: "memory");
    }
    __syncthreads();

    // ---- QK^T (S^T = K * Q^T), A-frags as clean b128 from subtiled LDS ----
    const u16* kb = &kv[cur][0];
    f32x4 s0 = {0,0,0,0}, s1 = {0,0,0,0};
    #pragma unroll
    for (int s=0;s<8;s++){
      int e = (2*s + (lg>>1))*512 + lq*16 + (lg&1)*8;
      bf16x8 ka0 = *(const bf16x8*)(kb + e);
      bf16x8 ka1 = *(const bf16x8*)(kb + e + 256);
      s0 = __builtin_amdgcn_mfma_f32_16x16x32_bf16(ka0, qf[s], s0, 0,0,0);
      s1 = __builtin_amdgcn_mfma_f32_16x16x32_bf16(ka1, qf[s], s1, 0,0,0);
    }
    // ---- exp (no max subtraction), accumulate denominator ----
    // lane holds scores for q=lq, keys {4lg+r} (s0) and {16+4lg+r} (s1)
    float p[8];
    #pragma unroll
    for (int r=0;r<4;r++){ p[r]   = __expf(s0[r]*0.0625f);
                           p[4+r] = __expf(s1[r]*0.0625f); }
    l_acc += (p[0]+p[1])+(p[2]+p[3])+((p[4]+p[5])+(p[6]+p[7]));
    // ---- P -> LDS (bf16), layout [q][key-in-32] (round-3 verified path) ----
    #pragma unroll
    for (int r=0;r<4;r++){
      pl[w][lq][lg*4+r]    = f2bf(p[r]);
      pl[w][lq][16+lg*4+r] = f2bf(p[4+r]);
    }
    // A-frag: P[q=lq][keys lg*8..lg*8+7]
    bf16x8 pa = *(const bf16x8*)(&pl[w][lq][lg*8]);
    // ---- PV: o[dt] (16q x 16d) += P(16x32) * V(32x16); B-frag scalar gather ----
    #pragma unroll
    for (int dt=0; dt<16; dt++){
      bf16x8 kbv;
      #pragma unroll
      for (int j=0;j<8;j++) kbv[j] = (short)kb[dt*512 + (lg*8+j)*16 + lq];
      o[dt] = __builtin_amdgcn_mfma_f32_16x16x32_bf16(pa, kbv, o[dt], 0,0,0);
    }
    __syncthreads();
  }
  #undef STAGE

  l_acc += __shfl_xor(l_acc, 16);
  l_acc += __shfl_xor(l_acc, 32);
  size_t qrow = (size_t)c*512 + qbase;
  if (lane < 16) pL[qrow + lq] = l_acc;
  // o[dt][r] = O[q = lg*4+r][d = dt*16+lq]
  #pragma unroll
  for (int dt=0; dt<16; dt++){
    #pragma unroll
    for (int r=0;r<4;r++){
      pO[(qrow + lg*4 + r)*256 + dt*16 + lq] = f2bf(o[dt][r]);
    }
  }
}

// ---------------- combine: plain sums + masked-key count + self + 1.5*q ----------------
__global__ __launch_bounds__(256) void attn_reduce(
    const u16* __restrict__ pO, const float* __restrict__ pL,
    const int* __restrict__ mask, const u16* __restrict__ qb,
    u16* __restrict__ attn_out)
{
  int q = blockIdx.x, d = threadIdx.x;
  int cnt0 = 0;
  for (int t=0;t<128;t++) cnt0 += (mask[t]==0) ? 1 : 0;
  float num = 0.f, den = 512.f*(float)cnt0;   // masked zero-keys: exp(0)=1 each
  for (int c=0;c<65;c++){
    bool valid = (c==64) || mask[2*c] || mask[2*c+1];
    if (!valid) continue;
    num += bf2f(pO[((size_t)c*512+q)*256 + d]);
    den += pL[(size_t)c*512+q];
  }
  float big = num/den;
  float sv = bf2f(pO[((size_t)65*512+q)*256 + d]) / pL[(size_t)65*512+q];
  attn_out[(size_t)q*256+d] = f2bf(big + 0.5f*sv + 1.5f*bf2f(qb[(size_t)q*256+d]));
}

extern "C" void kernel_launch(void* const* d_in, const int* in_sizes, int n_in,
                              void* d_out, int out_size, void* d_ws, size_t ws_size,
                              hipStream_t stream)
{
  const float* x    = (const float*)d_in[0];
  const float* ck   = (const float*)d_in[1];
  const float* ln1g = (const float*)d_in[2];
  const float* ln1b = (const float*)d_in[3];
  const float* ln2g = (const float*)d_in[4];
  const float* ln2b = (const float*)d_in[5];
  const float* wk   = (const float*)d_in[6];
  const float* wc   = (const float*)d_in[7];
  const float* apw  = (const float*)d_in[8];
  const float* apb  = (const float*)d_in[9];
  const float* fcw  = (const float*)d_in[10];
  const float* fcb  = (const float*)d_in[11];
  const float* pjw  = (const float*)d_in[12];
  const float* pjb  = (const float*)d_in[13];
  const int*   mask = (const int*)d_in[14];
  float* out = (float*)d_out;

  char* wsb = (char*)d_ws;
  float* x1    = (float*)(wsb + 0);          // 512x512 f32
  float* x2    = (float*)(wsb + 1048576);    // 512x512 f32
  u16*   aoutb = (u16*)  (wsb + 2097152);    // 512x256 bf16
  u16*   x2nb  = (u16*)  (wsb + 2359296);    // 512x512 bf16
  u16*   xgT   = (u16*)  (wsb + 2883584);    // 256x1536 bf16
  u16*   apT   = (u16*)  (wsb + 3670016);    // 512x256 bf16
  u16*   fcT   = (u16*)  (wsb + 3932160);    // 2048x512 bf16
  u16*   pjT   = (u16*)  (wsb + 6029312);    // 512x2048 bf16
  u16*   qbf   = (u16*)  (wsb + 8126464);    // 512x256 bf16
  u16*   kbf   = (u16*)  (wsb + 8388608);    // 66048x256 bf16
  float* pL    = (float*)(wsb + 42205184);   // 66x512 f32
  u16*   pO    = (u16*)  (wsb + 42340352);   // 66x512x256 bf16 (ends 59641856)
  u16*   wkcb  = (u16*)  (wsb + 42340352);   // 1024x1536 bf16, aliases pO (conv runs before attn)
  u16*   hb    = (u16*)  (wsb + 42340352);   // 512x2048 bf16, aliases pO (used after reduce)

  ln_kernel<false><<<512,256,0,stream>>>(x, ln1g, ln1b, x1, nullptr);
  xgT_kernel<<<256,256,0,stream>>>(x1, xgT);
  cvt_f2b<<<384,256,0,stream>>>(wk, wkcb);
  cvt_f2b<<<384,256,0,stream>>>(wc, wkcb + (size_t)512*1536);
  transcvt<<<dim3(16,8),256,0,stream>>>(apw, apT, 256, 512);
  transcvt<<<dim3(64,16),256,0,stream>>>(fcw, fcT, 512, 2048);
  transcvt<<<dim3(16,64),256,0,stream>>>(pjw, pjT, 2048, 512);
  cvt_cached<<<8192,256,0,stream>>>(ck, mask, kbf);

  // conv GEMM (stacked, round-3 verified): q (rows<512) + k_cur (rows>=512)
  gemm_bf<0,false,true><<<dim3(8,32),64,0,stream>>>(wkcb, xgT, nullptr, nullptr,
      nullptr, qbf, kbf + (size_t)65536*256, 512, 1024, 256, 1536);

  // attention partials: 64 cached chunks + conv chunk (c=64) + self chunk (c=65)
  attn_flash<<<dim3(66,8),256,0,stream>>>(qbf, kbf, mask, pO, pL);
  attn_reduce<<<512,256,0,stream>>>(pO, pL, mask, qbf, aoutb);

  // x2 = x1 + atten@ap_w + ap_b
  gemm_bf<0,true,false><<<dim3(16,16),64,0,stream>>>(aoutb, apT, apb, x1,
      x2, nullptr, nullptr, 512, 512, 512, 256);
  ln_kernel<true><<<512,256,0,stream>>>(x2, ln2g, ln2b, nullptr, x2nb);
  // h = swish(x2n@fc_w + fc_b)
  gemm_bf<1,false,true><<<dim3(64,16),64,0,stream>>>(x2nb, fcT, fcb, nullptr,
      nullptr, hb, hb, 4096, 512, 2048, 512);
  // out = x2 + h@proj_w + proj_b
  gemm_bf<0,true,false><<<dim3(16,16),64,0,stream>>>(hb, pjT, pjb, x2,
      out, nullptr, nullptr, 512, 512, 512, 2048);
}

// Round 7
// 168.605 us; speedup vs baseline: 3.2490x; 1.2917x over previous
//
#include <hip/hip_runtime.h>
#include <hip/hip_bf16.h>

typedef unsigned short u16;
typedef unsigned int u32;
typedef __attribute__((ext_vector_type(8))) short bf16x8;
typedef __attribute__((ext_vector_type(4))) short bf16x4;
typedef __attribute__((ext_vector_type(4))) float f32x4;
typedef __attribute__((ext_vector_type(8))) u16 u16x8;
typedef __attribute__((ext_vector_type(4))) u32 u32x4;

__device__ __forceinline__ u16 f2bf(float x){
  __hip_bfloat16 h = __float2bfloat16(x);
  return __builtin_bit_cast(u16, h);
}
__device__ __forceinline__ float bf2f(u16 u){
  __hip_bfloat16 h = __builtin_bit_cast(__hip_bfloat16, u);
  return __bfloat162float(h);
}

// ---------------- LayerNorm over rows of 512 ----------------
template<bool BF>
__global__ __launch_bounds__(256) void ln_kernel(const float* __restrict__ in,
    const float* __restrict__ g, const float* __restrict__ b,
    float* __restrict__ outf, u16* __restrict__ outb)
{
  int row = blockIdx.x, tid = threadIdx.x;
  const float* p = in + (size_t)row*512 + tid*2;
  float v0 = p[0], v1 = p[1];
  float s = v0+v1, ss = v0*v0+v1*v1;
  #pragma unroll
  for (int o=1;o<64;o<<=1){ s += __shfl_xor(s,o); ss += __shfl_xor(ss,o); }
  __shared__ float rs[4], rss[4];
  if ((tid&63)==0){ rs[tid>>6]=s; rss[tid>>6]=ss; }
  __syncthreads();
  s = rs[0]+rs[1]+rs[2]+rs[3]; ss = rss[0]+rss[1]+rss[2]+rss[3];
  float mean = s*(1.f/512.f);
  float var  = ss*(1.f/512.f) - mean*mean;
  float rstd = 1.f/sqrtf(var + 1e-5f);
  int d = tid*2;
  float o0 = (v0-mean)*rstd*g[d]   + b[d];
  float o1 = (v1-mean)*rstd*g[d+1] + b[d+1];
  if (BF){
    outb[(size_t)row*512+d]   = f2bf(o0);
    outb[(size_t)row*512+d+1] = f2bf(o1);
  } else {
    outf[(size_t)row*512+d]   = o0;
    outf[(size_t)row*512+d+1] = o1;
  }
}

// ---------------- conv input gather (transposed, bf16) ----------------
__global__ __launch_bounds__(256) void xgT_kernel(const float* __restrict__ x1, u16* __restrict__ xgT)
{
  int h = blockIdx.x, tid = threadIdx.x;
  #pragma unroll
  for (int rep=0;rep<6;rep++){
    int k = rep*256 + tid;
    int i = k/3, kk = k - i*3;
    int pos = 2*h - 1 + kk;
    float v = (pos >= 0 && pos < 512) ? x1[(size_t)i*512 + pos] : 0.f;
    xgT[(size_t)h*1536 + k] = f2bf(v);
  }
}

// ---------------- plain f32 -> bf16 convert (8 elems/thread) ----------------
__global__ __launch_bounds__(256) void cvt_f2b(const float* __restrict__ in, u16* __restrict__ out)
{
  size_t i = (size_t)(blockIdx.x*256 + threadIdx.x)*8;
  const float* p = in + i;
  u16x8 o;
  #pragma unroll
  for (int j=0;j<8;j++) o[j] = f2bf(p[j]);
  *(u16x8*)(out + i) = o;
}

// ---------------- transpose + convert: in f32 [K][N] -> out bf16 [N][K] ----------------
__global__ __launch_bounds__(256) void transcvt(const float* __restrict__ in, u16* __restrict__ out, int K, int N)
{
  __shared__ float t[32][33];
  int nb = blockIdx.x*32, kb = blockIdx.y*32;
  int tx = threadIdx.x & 31, ty = threadIdx.x >> 5;
  #pragma unroll
  for (int i=0;i<32;i+=8) t[ty+i][tx] = in[(size_t)(kb+ty+i)*N + nb+tx];
  __syncthreads();
  #pragma unroll
  for (int i=0;i<32;i+=8) out[(size_t)(nb+ty+i)*K + kb+tx] = f2bf(t[tx][ty+i]);
}

// ---------------- cached_k -> bf16 (skip masked t blocks) ----------------
__global__ __launch_bounds__(256) void cvt_cached(const float* __restrict__ ck,
    const int* __restrict__ mask, u16* __restrict__ kb)
{
  int flat = blockIdx.x*256 + threadIdx.x;   // 65536*32 total
  int row = flat >> 5, seg = flat & 31;
  if (mask[row>>9] == 0) return;
  const float* src = ck + (size_t)row*256 + seg*8;
  u16x8 o;
  #pragma unroll
  for (int j=0;j<8;j++) o[j] = f2bf(src[j]);
  *(u16x8*)(kb + (size_t)row*256 + seg*8) = o;
}

// ---------------- bf16 MFMA GEMM: 1 wave/block, 32x32 tile (round-3 verified) ----------------
template<int ACT, bool WF32, bool WBF>
__global__ __launch_bounds__(64) void gemm_bf(
    const u16* __restrict__ A, const u16* __restrict__ B,
    const float* __restrict__ bias, const float* __restrict__ resid,
    float* __restrict__ outF, u16* __restrict__ outB, u16* __restrict__ outB2,
    int rowSplit, int M, int N, int K)
{
  int lane = threadIdx.x;
  int lq = lane & 15, lg = lane >> 4;
  int m0 = blockIdx.y*32, n0 = blockIdx.x*32;
  f32x4 acc00={0,0,0,0}, acc01={0,0,0,0}, acc10={0,0,0,0}, acc11={0,0,0,0};
  const u16* pa0 = A + (size_t)(m0+lq)*K + lg*8;
  const u16* pa1 = pa0 + (size_t)16*K;
  const u16* pb0 = B + (size_t)(n0+lq)*K + lg*8;
  const u16* pb1 = pb0 + (size_t)16*K;
  #pragma unroll 2
  for (int k0=0;k0<K;k0+=32){
    bf16x8 a0 = *(const bf16x8*)(pa0+k0);
    bf16x8 a1 = *(const bf16x8*)(pa1+k0);
    bf16x8 b0 = *(const bf16x8*)(pb0+k0);
    bf16x8 b1 = *(const bf16x8*)(pb1+k0);
    acc00 = __builtin_amdgcn_mfma_f32_16x16x32_bf16(a0,b0,acc00,0,0,0);
    acc01 = __builtin_amdgcn_mfma_f32_16x16x32_bf16(a0,b1,acc01,0,0,0);
    acc10 = __builtin_amdgcn_mfma_f32_16x16x32_bf16(a1,b0,acc10,0,0,0);
    acc11 = __builtin_amdgcn_mfma_f32_16x16x32_bf16(a1,b1,acc11,0,0,0);
  }
  f32x4 accs[2][2] = {{acc00,acc01},{acc10,acc11}};
  #pragma unroll
  for (int mi=0;mi<2;mi++){
    #pragma unroll
    for (int r=0;r<4;r++){
      int row = m0 + mi*16 + lg*4 + r;
      #pragma unroll
      for (int ni=0;ni<2;ni++){
        int col = n0 + ni*16 + lq;
        float v = accs[mi][ni][r];
        if (bias)  v += bias[col];
        if (ACT==1) v = v/(1.f+__expf(-1.702f*v));
        if (resid) v += resid[(size_t)row*N+col];
        if (WF32) outF[(size_t)row*N+col] = v;
        if (WBF){
          if (row < rowSplit) outB[(size_t)row*N+col] = f2bf(v);
          else                outB2[(size_t)(row-rowSplit)*N+col] = f2bf(v);
        }
      }
    }
  }
}

// ---------------- flash attention partial kernel (v3: k-perm + canonical tr_read) ----------------
// grid (66, 16), 128 threads (2 waves, 16 q each): c<64 cached chunks (1024 keys),
// c=64 conv keys (512), c=65 self (keys=q).
// LDS per 32-key tile: elem(d,k) = (d>>4)*512 + k*16 + (d&15)  (16 KB, linear),
// staged via global_load_lds(16B) pre-swizzled source, double-buffered (round-6 verified).
// PV uses k-permutation: position (lg,j) <-> k in {4lg+j (j<4), 16+4lg+(j-4) (j>=4)}.
// A-frag = lane's own p values (QK^T D-layout supplies exactly these keys);
// B-frag = 2 canonical ds_read_b64_tr_b16 per d-subtile (addr = base + lane*8B).
__global__ __launch_bounds__(128) void attn_flash(
    const u16* __restrict__ qb, const u16* __restrict__ keys,
    const int* __restrict__ mask,
    u16* __restrict__ pO, float* __restrict__ pL)
{
  __shared__ u16 kv[2][8192];
  int tid = threadIdx.x;
  int w = tid >> 6, lane = tid & 63, lq = lane & 15, lg = lane >> 4;
  int c = blockIdx.x, qt = blockIdx.y;
  const u16* kp = keys;
  int kstart = c * 1024, off = 0, nt = 32;
  if (c == 65) { kp = qb; kstart = 0; nt = 16; }
  else if (c == 64) { kstart = 65536; nt = 16; }
  else {
    int m0 = mask[2*c], m1 = mask[2*c+1];
    if (!m0 && !m1) return;
    off = m0 ? 0 : 512;
    nt = ((m0 && m1) ? 32 : 16);
  }
  int qbase = qt*32 + w*16;

  bf16x8 qf[8];
  {
    const u16* qrow = qb + (size_t)(qbase+lq)*256 + lg*8;
    #pragma unroll
    for (int s=0;s<8;s++) qf[s] = *(const bf16x8*)(qrow + s*32);
  }
  f32x4 o[16];
  #pragma unroll
  for (int i=0;i<16;i++) o[i] = (f32x4){0,0,0,0};
  float l_acc = 0.f;

  auto kv3 = (__attribute__((address_space(3))) char*)&kv[0][0];
  unsigned kvaddr0 = (unsigned)(unsigned long long)kv3;
  const char* gbase = (const char*)kp + (size_t)(kstart+off)*512;

  // 128 threads: 8 reps x 128 lanes x 16B = 16KB per tile
  #define STAGE(i, b) { \
    const char* tb = gbase + (size_t)(i)*16384; \
    _Pragma("unroll") \
    for (int rep=0; rep<8; rep++){ \
      int slot = rep*128 + tid; \
      int goff = ((slot&63)>>1)*512 + ((slot>>6)*16 + (slot&1)*8)*2; \
      __builtin_amdgcn_global_load_lds( \
        (const __attribute__((address_space(1))) unsigned*)(tb + goff), \
        (__attribute__((address_space(3))) unsigned*)(kv3 + (b)*16384 + (rep*128 + (tid & ~63))*16), \
        16, 0, 0); \
    } }

  STAGE(0, 0);
  for (int i=0; i<nt; i++){
    int cur = i & 1;
    if (i+1 < nt){
      STAGE(i+1, cur^1);
      asm volatile("s_waitcnt vmcnt(8)" ::: "memory");
    } else {
      asm volatile("s_waitcnt vmcnt(0)" ::: "memory");
    }
    __syncthreads();

    // ---- QK^T (S^T = K * Q^T), A-frags as b128 from subtiled LDS (round-6 verified) ----
    const u16* kb = &kv[cur][0];
    f32x4 s0 = {0,0,0,0}, s1 = {0,0,0,0};
    #pragma unroll
    for (int s=0;s<8;s++){
      int e = (2*s + (lg>>1))*512 + lq*16 + (lg&1)*8;
      bf16x8 ka0 = *(const bf16x8*)(kb + e);
      bf16x8 ka1 = *(const bf16x8*)(kb + e + 256);
      s0 = __builtin_amdgcn_mfma_f32_16x16x32_bf16(ka0, qf[s], s0, 0,0,0);
      s1 = __builtin_amdgcn_mfma_f32_16x16x32_bf16(ka1, qf[s], s1, 0,0,0);
    }
    // ---- exp (no max subtraction); lane holds q=lq, keys {4lg+r} and {16+4lg+r} ----
    float p[8];
    #pragma unroll
    for (int r=0;r<4;r++){ p[r]   = __expf(s0[r]*0.0625f);
                           p[4+r] = __expf(s1[r]*0.0625f); }
    l_acc += (p[0]+p[1])+(p[2]+p[3])+((p[4]+p[5])+(p[6]+p[7]));
    // ---- A-frag = own p values (k-perm: position j <-> key {4lg+j, 16+4lg+(j-4)}) ----
    u32 w0 = (u32)f2bf(p[0]) | ((u32)f2bf(p[1])<<16);
    u32 w1 = (u32)f2bf(p[2]) | ((u32)f2bf(p[3])<<16);
    u32 w2 = (u32)f2bf(p[4]) | ((u32)f2bf(p[5])<<16);
    u32 w3 = (u32)f2bf(p[6]) | ((u32)f2bf(p[7])<<16);
    u32x4 fq = {w0,w1,w2,w3};
    bf16x8 pa = __builtin_bit_cast(bf16x8, fq);
    // ---- PV: B-frag via canonical tr_read (base + lane*8B); same k-perm ----
    // d-subtile dt at byte base dt*1024 is a [32k][16d] row-major bf16 tile;
    // read1 (rows 0-15): lane gets k=4lg+j, d=lq; read2 (+512B): k=16+4lg+j.
    unsigned trb = kvaddr0 + cur*16384 + lane*8;
    #pragma unroll
    for (int g2=0; g2<4; g2++){
      bf16x4 t0,t1,t2,t3,t4,t5,t6,t7;
      unsigned ab = trb + g2*4096;
      asm volatile(
        "ds_read_b64_tr_b16 %0, %8 offset:0\n\t"
        "ds_read_b64_tr_b16 %1, %8 offset:512\n\t"
        "ds_read_b64_tr_b16 %2, %8 offset:1024\n\t"
        "ds_read_b64_tr_b16 %3, %8 offset:1536\n\t"
        "ds_read_b64_tr_b16 %4, %8 offset:2048\n\t"
        "ds_read_b64_tr_b16 %5, %8 offset:2560\n\t"
        "ds_read_b64_tr_b16 %6, %8 offset:3072\n\t"
        "ds_read_b64_tr_b16 %7, %8 offset:3584\n\t"
        "s_waitcnt lgkmcnt(0)"
        : "=&v"(t0),"=&v"(t1),"=&v"(t2),"=&v"(t3),
          "=&v"(t4),"=&v"(t5),"=&v"(t6),"=&v"(t7)
        : "v"(ab));
      __builtin_amdgcn_sched_barrier(0);
      bf16x8 v0 = __builtin_shufflevector(t0,t1,0,1,2,3,4,5,6,7);
      bf16x8 v1 = __builtin_shufflevector(t2,t3,0,1,2,3,4,5,6,7);
      bf16x8 v2 = __builtin_shufflevector(t4,t5,0,1,2,3,4,5,6,7);
      bf16x8 v3 = __builtin_shufflevector(t6,t7,0,1,2,3,4,5,6,7);
      o[g2*4+0] = __builtin_amdgcn_mfma_f32_16x16x32_bf16(pa, v0, o[g2*4+0], 0,0,0);
      o[g2*4+1] = __builtin_amdgcn_mfma_f32_16x16x32_bf16(pa, v1, o[g2*4+1], 0,0,0);
      o[g2*4+2] = __builtin_amdgcn_mfma_f32_16x16x32_bf16(pa, v2, o[g2*4+2], 0,0,0);
      o[g2*4+3] = __builtin_amdgcn_mfma_f32_16x16x32_bf16(pa, v3, o[g2*4+3], 0,0,0);
    }
    __syncthreads();
  }
  #undef STAGE

  l_acc += __shfl_xor(l_acc, 16);
  l_acc += __shfl_xor(l_acc, 32);
  size_t qrow = (size_t)c*512 + qbase;
  if (lane < 16) pL[qrow + lq] = l_acc;
  // o[dt][r] = O[q = 4lg+r][d = dt*16+lq]
  #pragma unroll
  for (int dt=0; dt<16; dt++){
    #pragma unroll
    for (int r=0;r<4;r++){
      pO[(qrow + lg*4 + r)*256 + dt*16 + lq] = f2bf(o[dt][r]);
    }
  }
}

// ---------------- combine: plain sums + masked-key count + self + 1.5*q ----------------
__global__ __launch_bounds__(256) void attn_reduce(
    const u16* __restrict__ pO, const float* __restrict__ pL,
    const int* __restrict__ mask, const u16* __restrict__ qb,
    u16* __restrict__ attn_out)
{
  int q = blockIdx.x, d = threadIdx.x;
  int cnt0 = 0;
  for (int t=0;t<128;t++) cnt0 += (mask[t]==0) ? 1 : 0;
  float num = 0.f, den = 512.f*(float)cnt0;   // masked zero-keys: exp(0)=1 each
  for (int c=0;c<65;c++){
    bool valid = (c==64) || mask[2*c] || mask[2*c+1];
    if (!valid) continue;
    num += bf2f(pO[((size_t)c*512+q)*256 + d]);
    den += pL[(size_t)c*512+q];
  }
  float big = num/den;
  float sv = bf2f(pO[((size_t)65*512+q)*256 + d]) / pL[(size_t)65*512+q];
  attn_out[(size_t)q*256+d] = f2bf(big + 0.5f*sv + 1.5f*bf2f(qb[(size_t)q*256+d]));
}

extern "C" void kernel_launch(void* const* d_in, const int* in_sizes, int n_in,
                              void* d_out, int out_size, void* d_ws, size_t ws_size,
                              hipStream_t stream)
{
  const float* x    = (const float*)d_in[0];
  const float* ck   = (const float*)d_in[1];
  const float* ln1g = (const float*)d_in[2];
  const float* ln1b = (const float*)d_in[3];
  const float* ln2g = (const float*)d_in[4];
  const float* ln2b = (const float*)d_in[5];
  const float* wk   = (const float*)d_in[6];
  const float* wc   = (const float*)d_in[7];
  const float* apw  = (const float*)d_in[8];
  const float* apb  = (const float*)d_in[9];
  const float* fcw  = (const float*)d_in[10];
  const float* fcb  = (const float*)d_in[11];
  const float* pjw  = (const float*)d_in[12];
  const float* pjb  = (const float*)d_in[13];
  const int*   mask = (const int*)d_in[14];
  float* out = (float*)d_out;

  char* wsb = (char*)d_ws;
  float* x1    = (float*)(wsb + 0);          // 512x512 f32
  float* x2    = (float*)(wsb + 1048576);    // 512x512 f32
  u16*   aoutb = (u16*)  (wsb + 2097152);    // 512x256 bf16
  u16*   x2nb  = (u16*)  (wsb + 2359296);    // 512x512 bf16
  u16*   xgT   = (u16*)  (wsb + 2883584);    // 256x1536 bf16
  u16*   apT   = (u16*)  (wsb + 3670016);    // 512x256 bf16
  u16*   fcT   = (u16*)  (wsb + 3932160);    // 2048x512 bf16
  u16*   pjT   = (u16*)  (wsb + 6029312);    // 512x2048 bf16
  u16*   qbf   = (u16*)  (wsb + 8126464);    // 512x256 bf16
  u16*   kbf   = (u16*)  (wsb + 8388608);    // 66048x256 bf16
  float* pL    = (float*)(wsb + 42205184);   // 66x512 f32
  u16*   pO    = (u16*)  (wsb + 42340352);   // 66x512x256 bf16 (ends 59641856)
  u16*   wkcb  = (u16*)  (wsb + 42340352);   // 1024x1536 bf16, aliases pO (conv runs before attn)
  u16*   hb    = (u16*)  (wsb + 42340352);   // 512x2048 bf16, aliases pO (used after reduce)

  ln_kernel<false><<<512,256,0,stream>>>(x, ln1g, ln1b, x1, nullptr);
  xgT_kernel<<<256,256,0,stream>>>(x1, xgT);
  cvt_f2b<<<384,256,0,stream>>>(wk, wkcb);
  cvt_f2b<<<384,256,0,stream>>>(wc, wkcb + (size_t)512*1536);
  transcvt<<<dim3(16,8),256,0,stream>>>(apw, apT, 256, 512);
  transcvt<<<dim3(64,16),256,0,stream>>>(fcw, fcT, 512, 2048);
  transcvt<<<dim3(16,64),256,0,stream>>>(pjw, pjT, 2048, 512);
  cvt_cached<<<8192,256,0,stream>>>(ck, mask, kbf);

  // conv GEMM (stacked, round-3 verified): q (rows<512) + k_cur (rows>=512)
  gemm_bf<0,false,true><<<dim3(8,32),64,0,stream>>>(wkcb, xgT, nullptr, nullptr,
      nullptr, qbf, kbf + (size_t)65536*256, 512, 1024, 256, 1536);

  // attention partials: 64 cached chunks + conv chunk (c=64) + self chunk (c=65)
  attn_flash<<<dim3(66,16),128,0,stream>>>(qbf, kbf, mask, pO, pL);
  attn_reduce<<<512,256,0,stream>>>(pO, pL, mask, qbf, aoutb);

  // x2 = x1 + atten@ap_w + ap_b
  gemm_bf<0,true,false><<<dim3(16,16),64,0,stream>>>(aoutb, apT, apb, x1,
      x2, nullptr, nullptr, 512, 512, 512, 256);
  ln_kernel<true><<<512,256,0,stream>>>(x2, ln2g, ln2b, nullptr, x2nb);
  // h = swish(x2n@fc_w + fc_b)
  gemm_bf<1,false,true><<<dim3(64,16),64,0,stream>>>(x2nb, fcT, fcb, nullptr,
      nullptr, hb, hb, 4096, 512, 2048, 512);
  // out = x2 + h@proj_w + proj_b
  gemm_bf<0,true,false><<<dim3(16,16),64,0,stream>>>(hb, pjT, pjb, x2,
      out, nullptr, nullptr, 512, 512, 512, 2048);
}

// Round 8
// 157.037 us; speedup vs baseline: 3.4883x; 1.0737x over previous
//
#include <hip/hip_runtime.h>
#include <hip/hip_bf16.h>

typedef unsigned short u16;
typedef unsigned int u32;
typedef __attribute__((ext_vector_type(8))) short bf16x8;
typedef __attribute__((ext_vector_type(4))) short bf16x4;
typedef __attribute__((ext_vector_type(4))) float f32x4;
typedef __attribute__((ext_vector_type(8))) u16 u16x8;
typedef __attribute__((ext_vector_type(4))) u32 u32x4;

__device__ __forceinline__ u16 f2bf(float x){
  __hip_bfloat16 h = __float2bfloat16(x);
  return __builtin_bit_cast(u16, h);
}
__device__ __forceinline__ float bf2f(u16 u){
  __hip_bfloat16 h = __builtin_bit_cast(__hip_bfloat16, u);
  return __bfloat162float(h);
}

// ---------------- LayerNorm over rows of 512 ----------------
template<bool BF>
__global__ __launch_bounds__(256) void ln_kernel(const float* __restrict__ in,
    const float* __restrict__ g, const float* __restrict__ b,
    float* __restrict__ outf, u16* __restrict__ outb)
{
  int row = blockIdx.x, tid = threadIdx.x;
  const float* p = in + (size_t)row*512 + tid*2;
  float v0 = p[0], v1 = p[1];
  float s = v0+v1, ss = v0*v0+v1*v1;
  #pragma unroll
  for (int o=1;o<64;o<<=1){ s += __shfl_xor(s,o); ss += __shfl_xor(ss,o); }
  __shared__ float rs[4], rss[4];
  if ((tid&63)==0){ rs[tid>>6]=s; rss[tid>>6]=ss; }
  __syncthreads();
  s = rs[0]+rs[1]+rs[2]+rs[3]; ss = rss[0]+rss[1]+rss[2]+rss[3];
  float mean = s*(1.f/512.f);
  float var  = ss*(1.f/512.f) - mean*mean;
  float rstd = 1.f/sqrtf(var + 1e-5f);
  int d = tid*2;
  float o0 = (v0-mean)*rstd*g[d]   + b[d];
  float o1 = (v1-mean)*rstd*g[d+1] + b[d+1];
  if (BF){
    outb[(size_t)row*512+d]   = f2bf(o0);
    outb[(size_t)row*512+d+1] = f2bf(o1);
  } else {
    outf[(size_t)row*512+d]   = o0;
    outf[(size_t)row*512+d+1] = o1;
  }
}

// ---------------- conv input gather (transposed, bf16) ----------------
__global__ __launch_bounds__(256) void xgT_kernel(const float* __restrict__ x1, u16* __restrict__ xgT)
{
  int h = blockIdx.x, tid = threadIdx.x;
  #pragma unroll
  for (int rep=0;rep<6;rep++){
    int k = rep*256 + tid;
    int i = k/3, kk = k - i*3;
    int pos = 2*h - 1 + kk;
    float v = (pos >= 0 && pos < 512) ? x1[(size_t)i*512 + pos] : 0.f;
    xgT[(size_t)h*1536 + k] = f2bf(v);
  }
}

// ---------------- transpose+convert body (shared tile passed in) ----------------
__device__ __forceinline__ void transcvt_body(float (*t)[33],
    const float* __restrict__ in, u16* __restrict__ out, int K, int N, int bx, int by)
{
  int nb = bx*32, kb = by*32;
  int tx = threadIdx.x & 31, ty = threadIdx.x >> 5;
  #pragma unroll
  for (int i=0;i<32;i+=8) t[ty+i][tx] = in[(size_t)(kb+ty+i)*N + nb+tx];
  __syncthreads();
  #pragma unroll
  for (int i=0;i<32;i+=8) out[(size_t)(nb+ty+i)*K + kb+tx] = f2bf(t[tx][ty+i]);
}

// ---------------- fused prep: cvt_cached + wk/wc cvt + 3 weight transposes ----------------
__global__ __launch_bounds__(256) void prep_kernel(
    const float* __restrict__ wk, const float* __restrict__ wc,
    const float* __restrict__ apw, const float* __restrict__ fcw, const float* __restrict__ pjw,
    const float* __restrict__ ck, const int* __restrict__ mask,
    u16* __restrict__ wkcb, u16* __restrict__ apT, u16* __restrict__ fcT,
    u16* __restrict__ pjT, u16* __restrict__ kbf)
{
  __shared__ float t[32][33];
  int b = blockIdx.x, tid = threadIdx.x;
  if (b < 8192){                      // cached_k -> bf16 (skip masked t blocks)
    int flat = b*256 + tid;
    int row = flat >> 5, seg = flat & 31;
    if (mask[row>>9] == 0) return;
    const float* src = ck + (size_t)row*256 + seg*8;
    u16x8 o;
    #pragma unroll
    for (int j=0;j<8;j++) o[j] = f2bf(src[j]);
    *(u16x8*)(kbf + (size_t)row*256 + seg*8) = o;
  } else if (b < 8960){               // wk|wc -> wkcb (stacked 1024x1536)
    size_t i = (size_t)((b-8192)*256 + tid)*8;
    const size_t half = (size_t)512*1536;
    const float* src = (i < half) ? (wk + i) : (wc + (i - half));
    u16x8 o;
    #pragma unroll
    for (int j=0;j<8;j++) o[j] = f2bf(src[j]);
    *(u16x8*)(wkcb + i) = o;
  } else if (b < 9088){               // apw f32[256][512] -> apT bf16[512][256]
    int f = b - 8960;
    transcvt_body(t, apw, apT, 256, 512, f & 15, f >> 4);
  } else if (b < 10112){              // fcw f32[512][2048] -> fcT bf16[2048][512]
    int f = b - 9088;
    transcvt_body(t, fcw, fcT, 512, 2048, f & 63, f >> 6);
  } else {                            // pjw f32[2048][512] -> pjT bf16[512][2048]
    int f = b - 10112;
    transcvt_body(t, pjw, pjT, 2048, 512, f & 15, f >> 4);
  }
}

// ---------------- bf16 MFMA GEMM: 1 wave/block, 32x32 tile (round-3 verified) ----------------
template<int ACT, bool WF32, bool WBF>
__global__ __launch_bounds__(64) void gemm_bf(
    const u16* __restrict__ A, const u16* __restrict__ B,
    const float* __restrict__ bias, const float* __restrict__ resid,
    float* __restrict__ outF, u16* __restrict__ outB, u16* __restrict__ outB2,
    int rowSplit, int M, int N, int K)
{
  int lane = threadIdx.x;
  int lq = lane & 15, lg = lane >> 4;
  int m0 = blockIdx.y*32, n0 = blockIdx.x*32;
  f32x4 acc00={0,0,0,0}, acc01={0,0,0,0}, acc10={0,0,0,0}, acc11={0,0,0,0};
  const u16* pa0 = A + (size_t)(m0+lq)*K + lg*8;
  const u16* pa1 = pa0 + (size_t)16*K;
  const u16* pb0 = B + (size_t)(n0+lq)*K + lg*8;
  const u16* pb1 = pb0 + (size_t)16*K;
  #pragma unroll 2
  for (int k0=0;k0<K;k0+=32){
    bf16x8 a0 = *(const bf16x8*)(pa0+k0);
    bf16x8 a1 = *(const bf16x8*)(pa1+k0);
    bf16x8 b0 = *(const bf16x8*)(pb0+k0);
    bf16x8 b1 = *(const bf16x8*)(pb1+k0);
    acc00 = __builtin_amdgcn_mfma_f32_16x16x32_bf16(a0,b0,acc00,0,0,0);
    acc01 = __builtin_amdgcn_mfma_f32_16x16x32_bf16(a0,b1,acc01,0,0,0);
    acc10 = __builtin_amdgcn_mfma_f32_16x16x32_bf16(a1,b0,acc10,0,0,0);
    acc11 = __builtin_amdgcn_mfma_f32_16x16x32_bf16(a1,b1,acc11,0,0,0);
  }
  f32x4 accs[2][2] = {{acc00,acc01},{acc10,acc11}};
  #pragma unroll
  for (int mi=0;mi<2;mi++){
    #pragma unroll
    for (int r=0;r<4;r++){
      int row = m0 + mi*16 + lg*4 + r;
      #pragma unroll
      for (int ni=0;ni<2;ni++){
        int col = n0 + ni*16 + lq;
        float v = accs[mi][ni][r];
        if (bias)  v += bias[col];
        if (ACT==1) v = v/(1.f+__expf(-1.702f*v));
        if (resid) v += resid[(size_t)row*N+col];
        if (WF32) outF[(size_t)row*N+col] = v;
        if (WBF){
          if (row < rowSplit) outB[(size_t)row*N+col] = f2bf(v);
          else                outB2[(size_t)(row-rowSplit)*N+col] = f2bf(v);
        }
      }
    }
  }
}

// ---------------- flash attention partial kernel (v4: deep-pipelined tr_reads) ----------------
// grid (66, 16), 128 threads (2 waves, 16 q each): c<64 cached chunks (1024 keys),
// c=64 conv keys (512), c=65 self (keys=q).
// LDS per 32-key tile: elem(d,k) = (d>>4)*512 + k*16 + (d&15)  (16 KB, linear),
// staged via global_load_lds(16B) pre-swizzled source, double-buffered (round-6 verified).
// PV k-permutation + canonical tr_read (round-7 verified); NEW: tr_reads issued depth-2
// ahead with counted lgkmcnt(8) waits (max 16 outstanding, DS retires in order),
// exp/pack VALU overlapped with tr latency, sched_barrier(0) fences (rule #18).
__global__ __launch_bounds__(128) void attn_flash(
    const u16* __restrict__ qb, const u16* __restrict__ keys,
    const int* __restrict__ mask,
    u16* __restrict__ pO, float* __restrict__ pL)
{
  __shared__ u16 kv[2][8192];
  int tid = threadIdx.x;
  int w = tid >> 6, lane = tid & 63, lq = lane & 15, lg = lane >> 4;
  int c = blockIdx.x, qt = blockIdx.y;
  const u16* kp = keys;
  int kstart = c * 1024, off = 0, nt = 32;
  if (c == 65) { kp = qb; kstart = 0; nt = 16; }
  else if (c == 64) { kstart = 65536; nt = 16; }
  else {
    int m0 = mask[2*c], m1 = mask[2*c+1];
    if (!m0 && !m1) return;
    off = m0 ? 0 : 512;
    nt = ((m0 && m1) ? 32 : 16);
  }
  int qbase = qt*32 + w*16;

  bf16x8 qf[8];
  {
    const u16* qrow = qb + (size_t)(qbase+lq)*256 + lg*8;
    #pragma unroll
    for (int s=0;s<8;s++) qf[s] = *(const bf16x8*)(qrow + s*32);
  }
  f32x4 o[16];
  #pragma unroll
  for (int i=0;i<16;i++) o[i] = (f32x4){0,0,0,0};
  float l_acc = 0.f;

  auto kv3 = (__attribute__((address_space(3))) char*)&kv[0][0];
  unsigned kvaddr0 = (unsigned)(unsigned long long)kv3;
  const char* gbase = (const char*)kp + (size_t)(kstart+off)*512;

  // 128 threads: 8 reps x 128 lanes x 16B = 16KB per tile
  #define STAGE(i, b) { \
    const char* tb = gbase + (size_t)(i)*16384; \
    _Pragma("unroll") \
    for (int rep=0; rep<8; rep++){ \
      int slot = rep*128 + tid; \
      int goff = ((slot&63)>>1)*512 + ((slot>>6)*16 + (slot&1)*8)*2; \
      __builtin_amdgcn_global_load_lds( \
        (const __attribute__((address_space(1))) unsigned*)(tb + goff), \
        (__attribute__((address_space(3))) unsigned*)(kv3 + (b)*16384 + (rep*128 + (tid & ~63))*16), \
        16, 0, 0); \
    } }

  #define ISSUE8(T, ab) \
    asm volatile( \
      "ds_read_b64_tr_b16 %0, %8 offset:0\n\t" \
      "ds_read_b64_tr_b16 %1, %8 offset:512\n\t" \
      "ds_read_b64_tr_b16 %2, %8 offset:1024\n\t" \
      "ds_read_b64_tr_b16 %3, %8 offset:1536\n\t" \
      "ds_read_b64_tr_b16 %4, %8 offset:2048\n\t" \
      "ds_read_b64_tr_b16 %5, %8 offset:2560\n\t" \
      "ds_read_b64_tr_b16 %6, %8 offset:3072\n\t" \
      "ds_read_b64_tr_b16 %7, %8 offset:3584\n\t" \
      : "=&v"(T[0]),"=&v"(T[1]),"=&v"(T[2]),"=&v"(T[3]), \
        "=&v"(T[4]),"=&v"(T[5]),"=&v"(T[6]),"=&v"(T[7]) \
      : "v"(ab) : "memory")

  #define MFMA4(T, base) { \
    bf16x8 v0_ = __builtin_shufflevector(T[0],T[1],0,1,2,3,4,5,6,7); \
    bf16x8 v1_ = __builtin_shufflevector(T[2],T[3],0,1,2,3,4,5,6,7); \
    bf16x8 v2_ = __builtin_shufflevector(T[4],T[5],0,1,2,3,4,5,6,7); \
    bf16x8 v3_ = __builtin_shufflevector(T[6],T[7],0,1,2,3,4,5,6,7); \
    o[(base)+0] = __builtin_amdgcn_mfma_f32_16x16x32_bf16(pa, v0_, o[(base)+0], 0,0,0); \
    o[(base)+1] = __builtin_amdgcn_mfma_f32_16x16x32_bf16(pa, v1_, o[(base)+1], 0,0,0); \
    o[(base)+2] = __builtin_amdgcn_mfma_f32_16x16x32_bf16(pa, v2_, o[(base)+2], 0,0,0); \
    o[(base)+3] = __builtin_amdgcn_mfma_f32_16x16x32_bf16(pa, v3_, o[(base)+3], 0,0,0); \
  }

  STAGE(0, 0);
  for (int i=0; i<nt; i++){
    int cur = i & 1;
    if (i+1 < nt){
      STAGE(i+1, cur^1);
      asm volatile("s_waitcnt vmcnt(8)" ::: "memory");
    } else {
      asm volatile("s_waitcnt vmcnt(0)" ::: "memory");
    }
    __syncthreads();

    // ---- QK^T (S^T = K * Q^T), A-frags as b128 from subtiled LDS (round-6 verified) ----
    const u16* kb = &kv[cur][0];
    f32x4 s0 = {0,0,0,0}, s1 = {0,0,0,0};
    #pragma unroll
    for (int s=0;s<8;s++){
      int e = (2*s + (lg>>1))*512 + lq*16 + (lg&1)*8;
      bf16x8 ka0 = *(const bf16x8*)(kb + e);
      bf16x8 ka1 = *(const bf16x8*)(kb + e + 256);
      s0 = __builtin_amdgcn_mfma_f32_16x16x32_bf16(ka0, qf[s], s0, 0,0,0);
      s1 = __builtin_amdgcn_mfma_f32_16x16x32_bf16(ka1, qf[s], s1, 0,0,0);
    }
    // drain DS queue so counted lgkm waits below are exact (QK^T reads already consumed)
    asm volatile("s_waitcnt lgkmcnt(0)" ::: "memory");

    // ---- PV tr_reads: issue two groups ahead, then overlap exp/pack with latency ----
    unsigned trb = kvaddr0 + cur*16384 + lane*8;
    bf16x4 tA[8], tB[8], tC[8], tD[8];
    ISSUE8(tA, trb);
    ISSUE8(tB, trb + 4096);

    // ---- exp (no max subtraction); lane holds q=lq, keys {4lg+r} and {16+4lg+r} ----
    float p[8];
    #pragma unroll
    for (int r=0;r<4;r++){ p[r]   = __expf(s0[r]*0.0625f);
                           p[4+r] = __expf(s1[r]*0.0625f); }
    l_acc += (p[0]+p[1])+(p[2]+p[3])+((p[4]+p[5])+(p[6]+p[7]));
    // A-frag = own p values (k-perm: position j <-> key {4lg+j, 16+4lg+(j-4)})
    u32 w0 = (u32)f2bf(p[0]) | ((u32)f2bf(p[1])<<16);
    u32 w1 = (u32)f2bf(p[2]) | ((u32)f2bf(p[3])<<16);
    u32 w2 = (u32)f2bf(p[4]) | ((u32)f2bf(p[5])<<16);
    u32 w3 = (u32)f2bf(p[6]) | ((u32)f2bf(p[7])<<16);
    u32x4 fq = {w0,w1,w2,w3};
    bf16x8 pa = __builtin_bit_cast(bf16x8, fq);

    // ---- counted-wait pipeline: wait(8)=oldest group done; issue next behind ----
    asm volatile("s_waitcnt lgkmcnt(8)" ::: "memory");
    __builtin_amdgcn_sched_barrier(0);
    MFMA4(tA, 0);
    ISSUE8(tC, trb + 8192);
    asm volatile("s_waitcnt lgkmcnt(8)" ::: "memory");
    __builtin_amdgcn_sched_barrier(0);
    MFMA4(tB, 4);
    ISSUE8(tD, trb + 12288);
    asm volatile("s_waitcnt lgkmcnt(8)" ::: "memory");
    __builtin_amdgcn_sched_barrier(0);
    MFMA4(tC, 8);
    asm volatile("s_waitcnt lgkmcnt(0)" ::: "memory");
    __builtin_amdgcn_sched_barrier(0);
    MFMA4(tD, 12);
    __syncthreads();
  }
  #undef STAGE
  #undef ISSUE8
  #undef MFMA4

  l_acc += __shfl_xor(l_acc, 16);
  l_acc += __shfl_xor(l_acc, 32);
  size_t qrow = (size_t)c*512 + qbase;
  if (lane < 16) pL[qrow + lq] = l_acc;
  // o[dt][r] = O[q = 4lg+r][d = dt*16+lq]
  #pragma unroll
  for (int dt=0; dt<16; dt++){
    #pragma unroll
    for (int r=0;r<4;r++){
      pO[(qrow + lg*4 + r)*256 + dt*16 + lq] = f2bf(o[dt][r]);
    }
  }
}

// ---------------- combine: plain sums + masked-key count + self + 1.5*q ----------------
__global__ __launch_bounds__(256) void attn_reduce(
    const u16* __restrict__ pO, const float* __restrict__ pL,
    const int* __restrict__ mask, const u16* __restrict__ qb,
    u16* __restrict__ attn_out)
{
  int q = blockIdx.x, d = threadIdx.x;
  int cnt0 = 0;
  for (int t=0;t<128;t++) cnt0 += (mask[t]==0) ? 1 : 0;
  float num = 0.f, den = 512.f*(float)cnt0;   // masked zero-keys: exp(0)=1 each
  for (int c=0;c<65;c++){
    bool valid = (c==64) || mask[2*c] || mask[2*c+1];
    if (!valid) continue;
    num += bf2f(pO[((size_t)c*512+q)*256 + d]);
    den += pL[(size_t)c*512+q];
  }
  float big = num/den;
  float sv = bf2f(pO[((size_t)65*512+q)*256 + d]) / pL[(size_t)65*512+q];
  attn_out[(size_t)q*256+d] = f2bf(big + 0.5f*sv + 1.5f*bf2f(qb[(size_t)q*256+d]));
}

extern "C" void kernel_launch(void* const* d_in, const int* in_sizes, int n_in,
                              void* d_out, int out_size, void* d_ws, size_t ws_size,
                              hipStream_t stream)
{
  const float* x    = (const float*)d_in[0];
  const float* ck   = (const float*)d_in[1];
  const float* ln1g = (const float*)d_in[2];
  const float* ln1b = (const float*)d_in[3];
  const float* ln2g = (const float*)d_in[4];
  const float* ln2b = (const float*)d_in[5];
  const float* wk   = (const float*)d_in[6];
  const float* wc   = (const float*)d_in[7];
  const float* apw  = (const float*)d_in[8];
  const float* apb  = (const float*)d_in[9];
  const float* fcw  = (const float*)d_in[10];
  const float* fcb  = (const float*)d_in[11];
  const float* pjw  = (const float*)d_in[12];
  const float* pjb  = (const float*)d_in[13];
  const int*   mask = (const int*)d_in[14];
  float* out = (float*)d_out;

  char* wsb = (char*)d_ws;
  float* x1    = (float*)(wsb + 0);          // 512x512 f32
  float* x2    = (float*)(wsb + 1048576);    // 512x512 f32
  u16*   aoutb = (u16*)  (wsb + 2097152);    // 512x256 bf16
  u16*   x2nb  = (u16*)  (wsb + 2359296);    // 512x512 bf16
  u16*   xgT   = (u16*)  (wsb + 2883584);    // 256x1536 bf16
  u16*   apT   = (u16*)  (wsb + 3670016);    // 512x256 bf16
  u16*   fcT   = (u16*)  (wsb + 3932160);    // 2048x512 bf16
  u16*   pjT   = (u16*)  (wsb + 6029312);    // 512x2048 bf16
  u16*   qbf   = (u16*)  (wsb + 8126464);    // 512x256 bf16
  u16*   kbf   = (u16*)  (wsb + 8388608);    // 66048x256 bf16
  float* pL    = (float*)(wsb + 42205184);   // 66x512 f32
  u16*   pO    = (u16*)  (wsb + 42340352);   // 66x512x256 bf16 (ends 59641856)
  u16*   wkcb  = (u16*)  (wsb + 42340352);   // 1024x1536 bf16, aliases pO (conv runs before attn)
  u16*   hb    = (u16*)  (wsb + 42340352);   // 512x2048 bf16, aliases pO (used after reduce)

  ln_kernel<false><<<512,256,0,stream>>>(x, ln1g, ln1b, x1, nullptr);
  xgT_kernel<<<256,256,0,stream>>>(x1, xgT);
  prep_kernel<<<11136,256,0,stream>>>(wk, wc, apw, fcw, pjw, ck, mask,
      wkcb, apT, fcT, pjT, kbf);

  // conv GEMM (stacked, round-3 verified): q (rows<512) + k_cur (rows>=512)
  gemm_bf<0,false,true><<<dim3(8,32),64,0,stream>>>(wkcb, xgT, nullptr, nullptr,
      nullptr, qbf, kbf + (size_t)65536*256, 512, 1024, 256, 1536);

  // attention partials: 64 cached chunks + conv chunk (c=64) + self chunk (c=65)
  attn_flash<<<dim3(66,16),128,0,stream>>>(qbf, kbf, mask, pO, pL);
  attn_reduce<<<512,256,0,stream>>>(pO, pL, mask, qbf, aoutb);

  // x2 = x1 + atten@ap_w + ap_b
  gemm_bf<0,true,false><<<dim3(16,16),64,0,stream>>>(aoutb, apT, apb, x1,
      x2, nullptr, nullptr, 512, 512, 512, 256);
  ln_kernel<true><<<512,256,0,stream>>>(x2, ln2g, ln2b, nullptr, x2nb);
  // h = swish(x2n@fc_w + fc_b)
  gemm_bf<1,false,true><<<dim3(64,16),64,0,stream>>>(x2nb, fcT, fcb, nullptr,
      nullptr, hb, hb, 4096, 512, 2048, 512);
  // out = x2 + h@proj_w + proj_b
  gemm_bf<0,true,false><<<dim3(16,16),64,0,stream>>>(hb, pjT, pjb, x2,
      out, nullptr, nullptr, 512, 512, 512, 2048);
}